// Round 9
// baseline (787.430 us; speedup 1.0000x reference)
//
#include <hip/hip_runtime.h>
#include <stdint.h>

// CAN_Layer reduces exactly to: out[:, :2048] = out[:, 2048:] =
//   0.5 * (protein @ Wv_p + drug @ Wv_d)
// (seq-len 1 -> softmax over singleton axis == 1 -> attention = identity on V).
//
// Pipeline:
//   Pass 1a: cast+transpose Wv_p/Wv_d -> Wt bf16 [2048][4096] (B^T layout).
//   Pass 1b: cast protein|drug -> Abf bf16 [16384][4096].
//   Pass 2:  gemm8 — 256x256 tile, BK=64, 8 waves (2x4), m201 8-phase cadence:
//            4 quadrant phases/K-tile {reads -> [lgkm throttle] -> BAR ->
//            lgkmcnt(0) -> setprio MFMA x16 -> BAR}, stage exactly ONE
//            region (2 gll) per phase, ONE counted VMW(6) per tile at P3
//            (T4: counted-vs-drain +38-73%, m218). Row-XOR LDS swizzle
//            (0 conflicts, R2), chunked XCD swizzle (FETCH~ideal, R3).
//
// R9 vs R8 (303us, MfmaUtil 39.5% = the ~900TF m97-structure ceiling):
// R8's whole-tile weave had 1 sync/tile but coarse interleave. m201's fine
// phase cadence measures 62% MfmaUtil on the same chip/shape-class.
// R3 (373us) differed from m201 only in vmcnt cadence (4x VMW(8)/tile) and
// bunched stages — both fixed here.
//
// Stage ledger (tile T, buf b=T&1, per-wave gll units; verified by induction):
//  P0: stage A1(T+1)->nb | P1: A0(T+2)->b | P2: B0(T+2)->b | P3: B1(T+2)->b
//  At T-P3: outstanding = 6 (leftover {A0,B0,B1}(T+1)) + 8 = 14; VMW(6)
//  retires 8 oldest = {A0,B0,B1}(T+1) + A1(T+1) -> tile T+1 fully confirmed
//  one barrier before its P0 reads; leftover = {A0,B0,B1}(T+2). QED.
//  Overwrite: each stage issues >=1 end-BAR after last reader's LGW0:
//  A0 read P0 -> staged P1; B0 read P0 -> P2; B1 read P1 -> P3;
//  A1(nb) read T-1 P2 -> staged T P0.
//  Prologue: T0{A0,B0,B1,A1} + T1{A0,B0,B1} (14 gll); VMW(6) retires T0's 8;
//  leftover = {A0,B0,B1}(T1) = steady invariant. A1(T1) staged at T0-P0.
//  Tail: loop T=0..61 stages tiles 2..63 except A1(63), staged at epilogue
//  tile-62 P0; VMW(0) at 62-P3 confirms all of 63; tile 63 barrier-free.

typedef __attribute__((ext_vector_type(8))) short short8;
typedef __attribute__((ext_vector_type(4))) float float4v;
typedef __attribute__((ext_vector_type(2))) unsigned int uint2v;

typedef const __attribute__((address_space(1))) unsigned int* gp_t;
typedef __attribute__((address_space(3))) unsigned int* lp_t;

#define M_DIM 16384
#define N_DIM 2048
#define K_DIM 4096
#define OUT_LD 4096

static __device__ __forceinline__ unsigned int pack_bf16x2(float x, float y) {
  union { float f; unsigned int u; } a, b;
  a.f = x; b.f = y;
  unsigned int ua = a.u + 0x8000u;
  unsigned int ub = b.u + 0x8000u;
  return __builtin_amdgcn_perm(ub, ua, 0x07060302u);
}

static __device__ __forceinline__ unsigned short f2bf(float x) {
  union { float f; unsigned int u; } a; a.f = x;
  return (unsigned short)((a.u + 0x8000u) >> 16);
}

// ---- Pass 1a: Wt[n][k] = bf16(W[k][n]), W = Wv_p (k<2048) else Wv_d ----
__global__ __launch_bounds__(256)
void prep_wt(const float* __restrict__ Wp, const float* __restrict__ Wd,
             unsigned short* __restrict__ Wt) {
  __shared__ float tile[32][33];
  const int k0 = blockIdx.x * 32;
  const int n0 = blockIdx.y * 32;
  const int tx = threadIdx.x;
  const int ty = threadIdx.y;
  const float* W = (k0 < 2048) ? Wp : Wd;
  const int kk0 = (k0 < 2048) ? k0 : k0 - 2048;
#pragma unroll
  for (int i = 0; i < 4; ++i) {
    int r = ty * 4 + i;
    tile[r][tx] = W[(size_t)(kk0 + r) * 2048 + n0 + tx];
  }
  __syncthreads();
#pragma unroll
  for (int i = 0; i < 4; ++i) {
    int r = ty * 4 + i;
    Wt[(size_t)(n0 + r) * (size_t)K_DIM + k0 + tx] = f2bf(tile[tx][r]);
  }
}

// ---- Pass 1b: Abf[m][k] = bf16([protein | drug][m][k]) ----
__global__ __launch_bounds__(256)
void cast_a(const float* __restrict__ P, const float* __restrict__ Dg,
            unsigned int* __restrict__ Abf) {
  int idx = blockIdx.x * 256 + threadIdx.x;
  int row = idx >> 10;
  int j = (idx & 1023) << 2;
  const float* src = (j < 2048) ? (P + (size_t)row * 2048 + j)
                                : (Dg + (size_t)row * 2048 + (j - 2048));
  float4v v = *(const float4v*)src;
  uint2v o;
  o.x = pack_bf16x2(v.x, v.y);
  o.y = pack_bf16x2(v.z, v.w);
  *(uint2v*)(Abf + (size_t)row * 2048 + (j >> 1)) = o;
}

#define VMW(N) asm volatile("s_waitcnt vmcnt(" #N ")" ::: "memory")
#define LGW0() asm volatile("s_waitcnt lgkmcnt(0)" ::: "memory")
#define LGW8() asm volatile("s_waitcnt lgkmcnt(8)" ::: "memory")
#define BAR() __builtin_amdgcn_s_barrier()
#define SP1 __builtin_amdgcn_s_setprio(1);
#define SP0 __builtin_amdgcn_s_setprio(0);

#define LOAD_A(Ac, QM)                                                      \
  _Pragma("unroll") for (int i = 0; i < 4; ++i) {                           \
    af[i][0] = *(const short8*)&(Ac)[aoff + ((QM)*4 + i) * 1024 + c0];      \
    af[i][1] = *(const short8*)&(Ac)[aoff + ((QM)*4 + i) * 1024 + c1];      \
  }

#define LOAD_B2(dst, Bc, QN)                                                \
  _Pragma("unroll") for (int j = 0; j < 2; ++j) {                           \
    dst[j][0] = *(const short8*)&(Bc)[boff + ((QN)*2 + j) * 1024 + c0];     \
    dst[j][1] = *(const short8*)&(Bc)[boff + ((QN)*2 + j) * 1024 + c1];     \
  }

#define MFMA_Q(bset, QM, QN)                                                \
  _Pragma("unroll") for (int i = 0; i < 4; ++i)                             \
  _Pragma("unroll") for (int j = 0; j < 2; ++j) {                           \
    acc[(QM)*4 + i][(QN)*2 + j] = __builtin_amdgcn_mfma_f32_16x16x32_bf16(  \
        af[i][0], bset[j][0], acc[(QM)*4 + i][(QN)*2 + j], 0, 0, 0);        \
    acc[(QM)*4 + i][(QN)*2 + j] = __builtin_amdgcn_mfma_f32_16x16x32_bf16(  \
        af[i][1], bset[j][1], acc[(QM)*4 + i][(QN)*2 + j], 0, 0, 0);        \
  }

__global__ __launch_bounds__(512, 1)
void gemm8(const unsigned short* __restrict__ Abf,
           const unsigned short* __restrict__ Wt,
           float* __restrict__ out) {
  __shared__ unsigned short As[2][256 * 64];  // 64 KB
  __shared__ unsigned short Bs[2][256 * 64];  // 64 KB

  const int t = threadIdx.x;
  const int w = t >> 6, l = t & 63;
  const int wm = w >> 2, wn = w & 3;          // 2x4 wave grid
  const int lr = l & 15, q16 = l >> 4, xr = lr & 7;

  // Chunked XCD swizzle: XCD (bx&7) owns contiguous logical [x*64,(x+1)*64)
  const int bx = blockIdx.x;                  // 512 blocks
  const int logical = (bx & 7) * 64 + (bx >> 3);
  const int tn = logical & 7, tm = logical >> 3;
  const int m0 = tm << 8, n0 = tn << 8;

  // staging: row_in = t>>3, granule pos = t&7, swizzled src granule = pos^row
  const int srow = t >> 3;
  const int sk = (((t & 7) ^ (srow & 7)) << 3);
  const int brr = srow & 31;
  const int bsel = t >> 8;

  auto stage_a = [&](int buf, int k0, int h) {
#pragma unroll
    for (int sub = 0; sub < 2; ++sub) {
      const int row = m0 + sub * 128 + h * 64 + srow;
      const unsigned short* g = Abf + (size_t)row * K_DIM + (k0 + sk);
      const int ldsrow0 = sub * 128 + h * 64 + (w << 3);
      __builtin_amdgcn_global_load_lds((gp_t)(const void*)g,
                                       (lp_t)&As[buf][ldsrow0 * 64], 16, 0, 0);
    }
  };
  auto stage_b = [&](int buf, int k0, int nh) {
#pragma unroll
    for (int sub = 0; sub < 2; ++sub) {
      const int wnr = sub * 2 + bsel;
      const int ncol = n0 + wnr * 64 + nh * 32 + brr;
      const unsigned short* g = Wt + (size_t)ncol * K_DIM + (k0 + sk);
      const int ldsrow0 = wnr * 64 + nh * 32 + ((w & 3) << 3);
      __builtin_amdgcn_global_load_lds((gp_t)(const void*)g,
                                       (lp_t)&Bs[buf][ldsrow0 * 64], 16, 0, 0);
    }
  };

  float4v acc[8][4];
#pragma unroll
  for (int i = 0; i < 8; ++i)
#pragma unroll
    for (int j = 0; j < 4; ++j)
      acc[i][j] = (float4v){0.f, 0.f, 0.f, 0.f};

  const int aoff = (wm * 128 + lr) * 64;
  const int boff = (wn * 64 + lr) * 64;
  const int c0 = (q16 ^ xr) << 3;            // ks = 0 (swizzled granule)
  const int c1 = ((4 + q16) ^ xr) << 3;      // ks = 1

  // ---- prologue: T0 all 4 regions, then T1 {A0,B0,B1} (14 gll);
  //      VMW(6) retires T0's 8 -> T0 confirmed; leftover = steady invariant.
  stage_a(0, 0, 0);
  stage_b(0, 0, 0);
  stage_b(0, 0, 1);
  stage_a(0, 0, 1);
  stage_a(1, 64, 0);
  stage_b(1, 64, 0);
  stage_b(1, 64, 1);
  VMW(6);
  BAR();

  // ---- main loop: tiles 0..61 (62,63 in epilogue) ----
  short8 af[4][2];
  short8 b0r[2][2];
  short8 b1r[2][2];
  for (int tt = 0; tt < 62; ++tt) {
    const int buf = tt & 1;
    unsigned short* Ac = &As[buf][0];
    unsigned short* Bc = &Bs[buf][0];
    const int k1 = tt * 64 + 64;    // tile tt+1
    const int k2 = tt * 64 + 128;   // tile tt+2

    // P0: quadrant (0,0); 12 reads; stage A1(tt+1)->nb (last read tt-1 P2)
    LOAD_A(Ac, 0)
    LOAD_B2(b0r, Bc, 0)
    stage_a(buf ^ 1, k1, 1);
    LGW8();
    BAR(); LGW0();
    SP1 MFMA_Q(b0r, 0, 0) SP0
    BAR();

    // P1: quadrant (0,1); 4 reads; stage A0(tt+2)->b (last read P0)
    LOAD_B2(b1r, Bc, 1)
    stage_a(buf, k2, 0);
    BAR(); LGW0();
    SP1 MFMA_Q(b1r, 0, 1) SP0
    BAR();

    // P2: quadrant (1,1); 8 reads; stage B0(tt+2)->b (last read P0)
    LOAD_A(Ac, 1)
    stage_b(buf, k2, 0);
    BAR(); LGW0();
    SP1 MFMA_Q(b1r, 1, 1) SP0
    BAR();

    // P3: quadrant (1,0); 0 reads; stage B1(tt+2)->b (last read P1);
    //     ONE counted VMW(6) per tile -> tile tt+1 fully confirmed.
    stage_b(buf, k2, 1);
    BAR();
    SP1 MFMA_Q(b0r, 1, 0) SP0
    VMW(6);
    BAR();
  }

  // ---- epilogue tile 62 (buf0): stage A1(63) at P0; VMW(0) at P3 ----
  {
    unsigned short* Ac = &As[0][0];
    unsigned short* Bc = &Bs[0][0];

    LOAD_A(Ac, 0)
    LOAD_B2(b0r, Bc, 0)
    stage_a(1, 4032, 1);            // A1(63); region last read tt=61 P2
    LGW8();
    BAR(); LGW0();
    SP1 MFMA_Q(b0r, 0, 0) SP0
    BAR();

    LOAD_B2(b1r, Bc, 1)
    BAR(); LGW0();
    SP1 MFMA_Q(b1r, 0, 1) SP0
    BAR();

    LOAD_A(Ac, 1)
    BAR(); LGW0();
    SP1 MFMA_Q(b1r, 1, 1) SP0
    BAR();

    SP1 MFMA_Q(b0r, 1, 0) SP0
    VMW(0);                         // confirms {A0,B0,B1}(63) leftover + A1(63)
    BAR();
  }

  // ---- tile 63 (buf1): no stages, no barriers; compiler orders lgkm ----
  {
    unsigned short* Ac = &As[1][0];
    unsigned short* Bc = &Bs[1][0];
    SP1
    LOAD_A(Ac, 0)
    LOAD_B2(b0r, Bc, 0)
    MFMA_Q(b0r, 0, 0)
    LOAD_B2(b1r, Bc, 1)
    MFMA_Q(b1r, 0, 1)
    LOAD_A(Ac, 1)
    MFMA_Q(b1r, 1, 1)
    MFMA_Q(b0r, 1, 0)
    SP0
  }

  // ---- C write: col = lane&15, row = (lane>>4)*4 + reg; both output halves
  const int rbase = m0 + wm * 128 + q16 * 4;
  const int cbase = n0 + wn * 64 + lr;
#pragma unroll
  for (int f = 0; f < 8; ++f)
#pragma unroll
    for (int j = 0; j < 4; ++j) {
      const int row = rbase + f * 16;
      const int col = cbase + j * 16;
#pragma unroll
      for (int r = 0; r < 4; ++r) {
        float v = acc[f][j][r] * 0.5f;
        size_t o = (size_t)(row + r) * (size_t)OUT_LD + col;
        out[o] = v;
        out[o + N_DIM] = v;
      }
    }
}

// ---- mid fallback (ws holds Wt only): fp32-A m97-style GEMM ----
__global__ __launch_bounds__(256)
void gemm_k(const float* __restrict__ Ap, const float* __restrict__ Ad,
            const unsigned short* __restrict__ Wt,
            float* __restrict__ out) {
  __shared__ unsigned short As[128 * 64];
  __shared__ unsigned short Bsm[128 * 64];

  const int t = threadIdx.x;
  const int bx = blockIdx.x;
  const int tn = bx & 15, tm = bx >> 4;
  const int m0 = tm << 7, n0 = tn << 7;
  const int w = t >> 6, l = t & 63;
  const int wmm = w & 1, wnn = w >> 1;
  const int lr = l & 15, q = l >> 4;

  const int rB = t >> 3;
  const int kB = (t & 7) * 8;

  float4v acc[4][4];
#pragma unroll
  for (int i = 0; i < 4; ++i)
#pragma unroll
    for (int j = 0; j < 4; ++j)
      acc[i][j] = (float4v){0.f, 0.f, 0.f, 0.f};

  for (int k0 = 0; k0 < K_DIM; k0 += 64) {
#pragma unroll
    for (int i = 0; i < 4; ++i) {
      const unsigned short* g =
          Wt + (size_t)(n0 + i * 32 + rB) * (size_t)K_DIM + (k0 + kB);
      __builtin_amdgcn_global_load_lds((gp_t)(const void*)g,
                                       (lp_t)&Bsm[i * 2048 + w * 512], 16, 0, 0);
    }
    {
      const float* base;
      int kk;
      if (k0 < 2048) { base = Ap; kk = k0; } else { base = Ad; kk = k0 - 2048; }
      const int rA = t >> 4;
      const int cA = (t & 15) * 4;
#pragma unroll
      for (int i = 0; i < 8; ++i) {
        int m = i * 16 + rA;
        float4v v = *(const float4v*)(base + (size_t)(m0 + m) * 2048 + kk + cA);
        uint2v o;
        o.x = pack_bf16x2(v.x, v.y);
        o.y = pack_bf16x2(v.z, v.w);
        *(uint2v*)&As[m * 64 + cA] = o;
      }
    }
    __syncthreads();

#pragma unroll
    for (int ks = 0; ks < 2; ++ks) {
      short8 a2[4], b2[4];
#pragma unroll
      for (int i = 0; i < 4; ++i) {
        a2[i] = *(const short8*)&As[(wmm * 64 + i * 16 + lr) * 64 + ks * 32 + q * 8];
        b2[i] = *(const short8*)&Bsm[(wnn * 64 + i * 16 + lr) * 64 + ks * 32 + q * 8];
      }
#pragma unroll
      for (int i = 0; i < 4; ++i)
#pragma unroll
        for (int j = 0; j < 4; ++j)
          acc[i][j] = __builtin_amdgcn_mfma_f32_16x16x32_bf16(a2[i], b2[j],
                                                              acc[i][j], 0, 0, 0);
    }
    __syncthreads();
  }

#pragma unroll
  for (int i = 0; i < 4; ++i) {
    const int r0 = m0 + wmm * 64 + i * 16 + q * 4;
#pragma unroll
    for (int j = 0; j < 4; ++j) {
      const int c = n0 + wnn * 64 + j * 16 + lr;
#pragma unroll
      for (int r = 0; r < 4; ++r) {
        float v = acc[i][j][r] * 0.5f;
        size_t o = (size_t)(r0 + r) * (size_t)OUT_LD + c;
        out[o] = v;
        out[o + 2048] = v;
      }
    }
  }
}

// ---- insurance fallback (no usable ws): fp32 LDS-tiled vector GEMM ----
__global__ __launch_bounds__(256)
void gemm_fallback(const float* __restrict__ P, const float* __restrict__ Dg,
                   const float* __restrict__ Wp, const float* __restrict__ Wd,
                   float* __restrict__ out) {
  __shared__ float Asf[64][17];
  __shared__ float Bsf[16][65];
  const int bx = blockIdx.x;
  const int by = blockIdx.y;
  const int t = threadIdx.x;
  const int tc = t & 15, trw = t >> 4;
  const int m0 = by * 64, n0 = bx * 64;
  float accf[4][4] = {};
  for (int k0 = 0; k0 < 4096; k0 += 16) {
    const float* Asrc = (k0 < 2048) ? P : Dg;
    const float* Bsrc = (k0 < 2048) ? Wp : Wd;
    const int kk = k0 & 2047;
#pragma unroll
    for (int i = 0; i < 4; ++i) {
      int r = i * 16 + trw;
      Asf[r][tc] = Asrc[(size_t)(m0 + r) * 2048 + kk + tc];
    }
#pragma unroll
    for (int i = 0; i < 4; ++i) {
      int r = i * 4 + (t >> 6);
      int c = t & 63;
      Bsf[r][c] = Bsrc[(size_t)(kk + r) * 2048 + n0 + c];
    }
    __syncthreads();
#pragma unroll
    for (int k2 = 0; k2 < 16; ++k2) {
      float a[4], b[4];
#pragma unroll
      for (int i = 0; i < 4; ++i) a[i] = Asf[trw * 4 + i][k2];
#pragma unroll
      for (int j = 0; j < 4; ++j) b[j] = Bsf[k2][tc * 4 + j];
#pragma unroll
      for (int i = 0; i < 4; ++i)
#pragma unroll
        for (int j = 0; j < 4; ++j) accf[i][j] += a[i] * b[j];
    }
    __syncthreads();
  }
#pragma unroll
  for (int i = 0; i < 4; ++i)
#pragma unroll
    for (int j = 0; j < 4; ++j) {
      float v = accf[i][j] * 0.5f;
      size_t o = (size_t)(m0 + trw * 4 + i) * 4096 + n0 + tc * 4 + j;
      out[o] = v;
      out[o + 2048] = v;
    }
}

extern "C" void kernel_launch(void* const* d_in, const int* in_sizes, int n_in,
                              void* d_out, int out_size, void* d_ws, size_t ws_size,
                              hipStream_t stream) {
  // setup_inputs order: protein, drug, mask_prot, mask_drug,
  //                     Wq_p, Wk_p, Wv_p, Wq_d, Wk_d, Wv_d
  const float* protein = (const float*)d_in[0];
  const float* drug    = (const float*)d_in[1];
  const float* Wv_p    = (const float*)d_in[6];
  const float* Wv_d    = (const float*)d_in[9];
  float* out = (float*)d_out;

  const size_t wt_bytes = (size_t)N_DIM * K_DIM * sizeof(unsigned short);  // 16.8 MB
  const size_t a_bytes  = (size_t)M_DIM * K_DIM * sizeof(unsigned short);  // 134 MB

  if (ws_size >= wt_bytes) {
    unsigned short* Wt = (unsigned short*)d_ws;
    prep_wt<<<dim3(128, 64), dim3(32, 8), 0, stream>>>(Wv_p, Wv_d, Wt);
    if (ws_size >= wt_bytes + a_bytes) {
      unsigned int* Abf = (unsigned int*)((char*)d_ws + wt_bytes);
      cast_a<<<65536, 256, 0, stream>>>(protein, drug, Abf);
      gemm8<<<512, 512, 0, stream>>>((const unsigned short*)Abf, Wt, out);
    } else {
      gemm_k<<<2048, 256, 0, stream>>>(protein, drug, Wt, out);
    }
  } else {
    gemm_fallback<<<dim3(32, 256), 256, 0, stream>>>(protein, drug, Wv_p, Wv_d, out);
  }
}